// Round 5
// baseline (331.297 us; speedup 1.0000x reference)
//
#include <hip/hip_runtime.h>

// Bilinear 2x upsample, NHWC fp32.
// in : (8, 256, 256, 32)  = 64 MiB
// out: (8, 512, 512, 32)  = 256 MiB
//
// R6: fill-shaped store streams. Evidence so far: three structurally
// different kernels (one-shot 6-load, +swizzle/NT, rolling-window 2-load)
// all land at kernel ~121-141 us (~2.5 TB/s) while the harness fill hits
// 6.4 TB/s at 9.9% occupancy with ~800 long-lived waves each streaming a
// contiguous ~1.3 MB slab. Traffic is already ideal (R4: FETCH 36.6 MB,
// WRITE 256 MiB). The one axis never changed: store-stream granularity —
// we always had ~2048+ blocks writing tiny scattered 4-8 KB regions.
// Here: 1024 blocks (4/CU), each owns a CONTIGUOUS 256 KB output slab
// (one n, output rows [4*jc, 4*jc+4)) and marches linearly in ox, so the
// chip-wide write stream is ~1024 fat sequential streams, like the fill.
// Reads/arithmetic/coalescing identical to R2 (proven non-limiting).

#define IH 256
#define IW 256
#define OHW 512
#define C4 8        // 32 channels / 4 floats per float4

typedef float f4 __attribute__((ext_vector_type(4)));

__global__ __launch_bounds__(256) void bilinear2x_kernel(
    const float* __restrict__ img, float* __restrict__ out) {
    // grid: 1024 = jc(128) x n(8). Block owns output rows [4jc, 4jc+4) of n.
    unsigned bx = blockIdx.x;
    unsigned jc = bx & 127u;
    unsigned n  = bx >> 7;

    unsigned c4  = threadIdx.x & (C4 - 1);
    unsigned oxl = threadIdx.x >> 3;           // 0..31

    const f4* base = (const f4*)img + (size_t)n * (IH * IW * C4);
    f4* ob = (f4*)out;
    const size_t rowstep = (size_t)OHW * C4;

    for (int tj = 0; tj < 2; ++tj) {
        int j = (int)(jc * 2u) + tj;           // input row pair index
        // rows j-1, j, j+1 (clamped) — wave-uniform, lives in SGPRs
        int rA = j - 1; if (rA < 0) rA = 0;
        int rC = j + 1; if (rC > IH - 1) rC = IH - 1;
        const f4* pA = base + (size_t)rA * (IW * C4);
        const f4* pB = base + (size_t)j  * (IW * C4);
        const f4* pC = base + (size_t)rC * (IW * C4);
        size_t oeRow = ((size_t)n * OHW + 2 * (size_t)j) * rowstep + c4;

#pragma unroll 4
        for (int oxc = 0; oxc < 16; ++oxc) {
            unsigned ox = (unsigned)oxc * 32u + oxl;
            // x weights: gx = max(0.5*ox - 0.25, 0)
            float gx = fmaxf(0.5f * (float)ox - 0.25f, 0.0f);
            int x0 = (int)gx;
            float w0 = gx - (float)x0;
            int x1 = x0 + (x0 < IW - 1);
            float w1 = 1.0f - w0;
            size_t o0 = (size_t)x0 * C4 + c4;
            size_t o1 = (size_t)x1 * C4 + c4;

            f4 a0 = pA[o0], a1 = pA[o1];
            f4 b0 = pB[o0], b1 = pB[o1];
            f4 c0 = pC[o0], c1 = pC[o1];

            f4 ra = w1 * a0 + w0 * a1;
            f4 rb = w1 * b0 + w0 * b1;
            f4 rc = w1 * c0 + w0 * c1;

            // even (oy=2j): 0.25*A + 0.75*B ; odd (oy=2j+1): 0.75*B + 0.25*C
            f4 re = 0.25f * ra + 0.75f * rb;
            f4 ro = 0.75f * rb + 0.25f * rc;

            size_t oe = oeRow + (size_t)ox * C4;
            ob[oe] = re;
            ob[oe + rowstep] = ro;
        }
    }
}

extern "C" void kernel_launch(void* const* d_in, const int* in_sizes, int n_in,
                              void* d_out, int out_size, void* d_ws, size_t ws_size,
                              hipStream_t stream) {
    const float* img = (const float*)d_in[0];
    float* out = (float*)d_out;
    // 8(n) * 128(jc) = 1024 blocks of 256 threads; 4 blocks/CU, each block
    // writes one contiguous 256 KB output slab.
    dim3 grid(1024);
    dim3 block(256);
    bilinear2x_kernel<<<grid, block, 0, stream>>>(img, out);
}

// Round 6
// 308.459 us; speedup vs baseline: 1.0740x; 1.0740x over previous
//
#include <hip/hip_runtime.h>

// Bilinear 2x upsample, NHWC fp32.
// in : (8, 256, 256, 32)  = 64 MiB
// out: (8, 512, 512, 32)  = 256 MiB
//
// R7: single-variable A/B vs the 309.2 us R2 best — EXACT R2 kernel with
// non-temporal stores and nothing else changed.
// Evidence trail: traffic is ideal (R4: FETCH 36.6 MB, WRITE 256 MiB) but
// four structurally different kernels (one-shot, rolling-window, fill-shaped
// slab, swizzled) all flat-line at ~2.5 TB/s effective — the signature of a
// path ceiling, not a schedule problem. Arithmetic: stores that allocate in
// the per-XCD L2 at ~128 B/cyc/XCD drain at 8*128B*2.4GHz ~= 2.46 TB/s --
// exactly the observed band. The 6.4 TB/s rocclr fill uses streaming
// stores. R3 tested NT only bundled with the (likely harmful) XCD swizzle;
// this round un-bundles it.

#define IH 256
#define IW 256
#define OHW 512
#define C4 8        // 32 channels / 4 floats per float4

typedef float f4 __attribute__((ext_vector_type(4)));

__global__ __launch_bounds__(256) void bilinear2x_kernel(
    const float* __restrict__ img, float* __restrict__ out) {
    unsigned tid = blockIdx.x * 256u + threadIdx.x;

    unsigned c4 = tid & (C4 - 1);          // float4 index within channels
    unsigned ox = (tid >> 3) & (OHW - 1);  // output x
    unsigned j  = (tid >> 12) & (IH - 1);  // output y pair index: oy = 2j, 2j+1
    unsigned n  = tid >> 20;

    // x weights: gx = max(0.5*ox - 0.25, 0)
    float gx = fmaxf(0.5f * (float)ox - 0.25f, 0.0f);
    int x0 = (int)gx;                      // trunc == floor (gx >= 0)
    float w0 = gx - (float)x0;
    int x1 = x0 + (x0 < IW - 1);
    float w1 = 1.0f - w0;

    // input rows j-1, j, j+1 (clamped). Clamping reproduces the reference
    // edge cases: j=0 -> even output = row0 exactly; j=255 -> odd = row255.
    int rA = (int)j - 1; rA = rA < 0 ? 0 : rA;
    int rB = (int)j;
    int rC = (int)j + 1; rC = rC > IH - 1 ? IH - 1 : rC;

    const f4* base = (const f4*)img;
    size_t nb = (size_t)n * (IH * IW * C4);
    const f4* pA = base + nb + (size_t)rA * (IW * C4);
    const f4* pB = base + nb + (size_t)rB * (IW * C4);
    const f4* pC = base + nb + (size_t)rC * (IW * C4);
    size_t o0 = (size_t)x0 * C4 + c4;
    size_t o1 = (size_t)x1 * C4 + c4;

    f4 a0 = pA[o0], a1 = pA[o1];
    f4 b0 = pB[o0], b1 = pB[o1];
    f4 c0 = pC[o0], c1 = pC[o1];

    // x-interpolate each row
    f4 ra = w1 * a0 + w0 * a1;
    f4 rb = w1 * b0 + w0 * b1;
    f4 rc = w1 * c0 + w0 * c1;

    // y-combine: even (oy=2j) = 0.25*A + 0.75*B ; odd (oy=2j+1) = 0.75*B + 0.25*C
    f4 re = 0.25f * ra + 0.75f * rb;
    f4 ro = 0.75f * rb + 0.25f * rc;

    // stores: out[(n, 2j, ox, c4)] and out[(n, 2j+1, ox, c4)] — NON-TEMPORAL
    f4* ob = (f4*)out;
    size_t oe = (((size_t)n * OHW + 2 * j) * OHW + ox) * C4 + c4;
    __builtin_nontemporal_store(re, ob + oe);
    __builtin_nontemporal_store(ro, ob + oe + (size_t)OHW * C4);
}

extern "C" void kernel_launch(void* const* d_in, const int* in_sizes, int n_in,
                              void* d_out, int out_size, void* d_ws, size_t ws_size,
                              hipStream_t stream) {
    const float* img = (const float*)d_in[0];
    float* out = (float*)d_out;
    // threads: 8 * 256(j) * 512(ox) * 8(c4) = 8,388,608
    const unsigned total = 8u * 256u * 512u * 8u;
    dim3 grid(total / 256u);
    dim3 block(256);
    bilinear2x_kernel<<<grid, block, 0, stream>>>(img, out);
}